// Round 3
// baseline (1015.892 us; speedup 1.0000x reference)
//
#include <hip/hip_runtime.h>

constexpr int B = 4, C = 16, H = 512, W = 512;
constexpr int HW = H * W;
constexpr int TS = 32;                   // output tile edge
constexpr int TX = W / TS, TYN = H / TS; // 16 x 16 tiles per image
constexpr int NBINS = B * TYN * TX;      // 1024
constexpr int CAP = 2048;                // entry slots per bin (expected ~1090)
// ws layout: u32 cnt[NBINS]; u32 entries[NBINS][CAP]

// ---------------- Phase 1: bin source pixels by destination tile ----------------
__global__ __launch_bounds__(256) void bin_kernel(
    const float* __restrict__ flow, const float* __restrict__ im0,
    unsigned* __restrict__ cnt, unsigned* __restrict__ entries,
    float* __restrict__ out)
{
    int idx = blockIdx.x * 256 + threadIdx.x;
    if (idx >= B * HW) return;
    float2 f = reinterpret_cast<const float2*>(flow)[idx];
    int sx = idx & (W - 1);
    int sy = (idx >> 9) & (H - 1);
    int b  = idx >> 18;

    float xd = (float)sx + f.x;
    float yd = (float)sy + f.y;
    float xff = floorf(xd), yff = floorf(yd);
    // reference: keep only if ALL four corners in-bounds
    if (!(xff >= 0.0f && yff >= 0.0f &&
          xff <= (float)(W - 2) && yff <= (float)(H - 2))) return;
    int xf = (int)xff, yf = (int)yff;

    int txf = xf >> 5, txc = (xf + 1) >> 5;
    int tyf = yf >> 5, tyc = (yf + 1) >> 5;
    unsigned packed = ((unsigned)(sy * W + sx)) << 4;

    for (int i = 0; i < 2; ++i) {
        int ty = i ? tyc : tyf;
        if (i && tyc == tyf) break;
        for (int j = 0; j < 2; ++j) {
            int tx = j ? txc : txf;
            if (j && txc == txf) break;
            int mask = 0;
            if (tyf == ty && txf == tx) mask |= 1;  // nw
            if (tyf == ty && txc == tx) mask |= 2;  // ne
            if (tyc == ty && txf == tx) mask |= 4;  // sw
            if (tyc == ty && txc == tx) mask |= 8;  // se
            int bin = (b * TYN + ty) * TX + tx;
            unsigned slot = atomicAdd(&cnt[bin], 1u);
            if (slot < CAP) {
                entries[(size_t)bin * CAP + slot] = packed | (unsigned)mask;
            } else {
                // overflow fallback (statistically never): direct global atomics
                float ax = xd - xff, ay = yd - yff;
                float w0 = (1.f - ax) * (1.f - ay), w1 = ax * (1.f - ay);
                float w2 = (1.f - ax) * ay,         w3 = ax * ay;
                size_t base = (size_t)b * C * HW;
                int d00 = yf * W + xf;
                for (int c = 0; c < C; ++c) {
                    float v = im0[base + (size_t)c * HW + sy * W + sx];
                    float* o = out + base + (size_t)c * HW + d00;
                    if (mask & 1) atomicAdd(o,         v * w0);
                    if (mask & 2) atomicAdd(o + 1,     v * w1);
                    if (mask & 4) atomicAdd(o + W,     v * w2);
                    if (mask & 8) atomicAdd(o + W + 1, v * w3);
                }
            }
        }
    }
}

// ---------------- Phase 2: per-tile accumulation, all 16 channels in LDS ----------------
__global__ __launch_bounds__(256) void accum_kernel(
    const float* __restrict__ flow, const float* __restrict__ im0,
    const unsigned* __restrict__ cnt, const unsigned* __restrict__ entries,
    float* __restrict__ out)
{
    __shared__ float acc[C * TS * TS];   // 16*32*32*4 = 64 KB
    const int bin = blockIdx.x;
    const int tid = threadIdx.x;
    const int b  = bin >> 8;
    const int ty = (bin >> 4) & 15;
    const int tx = bin & 15;
    const int y0 = ty * TS, x0 = tx * TS;

    for (int i = tid; i < C * TS * TS; i += 256) acc[i] = 0.0f;
    __syncthreads();

    const int n = min((int)cnt[bin], CAP);
    const unsigned* list = entries + (size_t)bin * CAP;
    const float* flowb = flow + (size_t)b * HW * 2;
    const float* im0b  = im0  + (size_t)b * C * HW;

    for (int i = tid; i < n; i += 256) {
        unsigned e = list[i];
        int mask = (int)(e & 15u);
        int s = (int)(e >> 4);               // sy*W + sx
        int sx = s & (W - 1);
        int sy = s >> 9;

        float2 f = reinterpret_cast<const float2*>(flowb)[s];
        float xd = (float)sx + f.x;
        float yd = (float)sy + f.y;
        float xff = floorf(xd), yff = floorf(yd);
        int xf = (int)xff, yf = (int)yff;
        float ax = xd - xff, ay = yd - yff;
        float w0 = (1.f - ax) * (1.f - ay), w1 = ax * (1.f - ay);
        float w2 = (1.f - ax) * ay,         w3 = ax * ay;
        int l0 = (yf - y0) * TS + (xf - x0);   // nw local offset (valid iff bit0)

        float v[C];
        #pragma unroll
        for (int c = 0; c < C; ++c) v[c] = im0b[(size_t)c * HW + s];

        #pragma unroll
        for (int c = 0; c < C; ++c) {
            float* a = acc + c * (TS * TS);
            if (mask & 1) atomicAdd(&a[l0],          v[c] * w0);
            if (mask & 2) atomicAdd(&a[l0 + 1],      v[c] * w1);
            if (mask & 4) atomicAdd(&a[l0 + TS],     v[c] * w2);
            if (mask & 8) atomicAdd(&a[l0 + TS + 1], v[c] * w3);
        }
    }
    __syncthreads();

    // flush: exclusive tile ownership -> plain float4 RMW (out may hold
    // overflow-fallback contributions, so read-modify-write)
    size_t outb = (size_t)b * C * HW;
    for (int i = tid; i < (C * TS * TS) / 4; i += 256) {  // 4096 float4
        int c   = i >> 8;          // 256 float4 per channel
        int rem = i & 255;
        int y   = rem >> 3;        // 8 float4 per row
        int x4  = (rem & 7) * 4;
        float4 a = *reinterpret_cast<const float4*>(&acc[c * TS * TS + y * TS + x4]);
        float* op = out + outb + (size_t)c * HW + (size_t)(y0 + y) * W + (x0 + x4);
        float4 cur = *reinterpret_cast<float4*>(op);
        cur.x += a.x; cur.y += a.y; cur.z += a.z; cur.w += a.w;
        *reinterpret_cast<float4*>(op) = cur;
    }
}

// ---------------- Safety fallback (ws too small): direct-atomic kernel ----------------
__global__ __launch_bounds__(256) void warp_naive_kernel(
    const float* __restrict__ im0, const float* __restrict__ flow,
    float* __restrict__ out)
{
    int idx = blockIdx.x * 256 + threadIdx.x;
    if (idx >= B * HW) return;
    int w = idx & (W - 1);
    int h = (idx >> 9) & (H - 1);
    int b = idx >> 18;
    float2 f = reinterpret_cast<const float2*>(flow)[idx];
    float xd = (float)w + f.x, yd = (float)h + f.y;
    float xff = floorf(xd), yff = floorf(yd);
    if (!(xff >= 0.0f && yff >= 0.0f &&
          xff <= (float)(W - 2) && yff <= (float)(H - 2))) return;
    int xf = (int)xff, yf = (int)yff;
    float ax = xd - xff, ay = yd - yff;
    float w0 = (1.f - ax) * (1.f - ay), w1 = ax * (1.f - ay);
    float w2 = (1.f - ax) * ay,         w3 = ax * ay;
    size_t plane0 = (size_t)b * C * HW;
    size_t srcoff = plane0 + (size_t)h * W + w;
    int d00 = yf * W + xf;
    for (int c = 0; c < C; ++c) {
        float v = im0[srcoff + (size_t)c * HW];
        float* o = out + plane0 + (size_t)c * HW + d00;
        atomicAdd(o,         v * w0);
        atomicAdd(o + 1,     v * w1);
        atomicAdd(o + W,     v * w2);
        atomicAdd(o + W + 1, v * w3);
    }
}

extern "C" void kernel_launch(void* const* d_in, const int* in_sizes, int n_in,
                              void* d_out, int out_size, void* d_ws, size_t ws_size,
                              hipStream_t stream) {
    const float* im0  = (const float*)d_in[0];
    const float* flow = (const float*)d_in[1];
    float* out = (float*)d_out;

    hipMemsetAsync(out, 0, (size_t)out_size * sizeof(float), stream);

    size_t need = (size_t)NBINS * 4 + (size_t)NBINS * CAP * 4;
    constexpr int total = B * HW;
    if (ws_size < need) {
        warp_naive_kernel<<<(total + 255) / 256, 256, 0, stream>>>(im0, flow, out);
        return;
    }

    unsigned* cnt = (unsigned*)d_ws;
    unsigned* entries = cnt + NBINS;
    hipMemsetAsync(cnt, 0, NBINS * sizeof(unsigned), stream);

    bin_kernel<<<(total + 255) / 256, 256, 0, stream>>>(flow, im0, cnt, entries, out);
    accum_kernel<<<NBINS, 256, 0, stream>>>(flow, im0, cnt, entries, out);
}

// Round 4
// 389.431 us; speedup vs baseline: 2.6087x; 2.6087x over previous
//
#include <hip/hip_runtime.h>

constexpr int B = 4, C = 16, H = 512, W = 512;
constexpr int HW = H * W;
constexpr int TS = 32, TX = 16, TYN = 16;
constexpr int NBINS = B * TYN * TX;   // 1024
constexpr int CAP   = 1600;           // slots per bin (expected max ~1250)
constexpr int CSTR  = 16;             // counter stride in u32 -> 64B per counter
constexpr int CPB   = 8;              // channels per accum block (32 KB LDS)

// ---- direct global-atomic splat (overflow / fallback paths) ----
__device__ __forceinline__ void direct_splat(
    const float* __restrict__ im0, float* __restrict__ out,
    int b, int s, int xf, int yf,
    float w0, float w1, float w2, float w3, unsigned mask)
{
    size_t base = (size_t)b * C * HW;
    int d00 = yf * W + xf;
    for (int c = 0; c < C; ++c) {
        float v = im0[base + (size_t)c * HW + s];
        float* o = out + base + (size_t)c * HW + d00;
        if (mask & 1u) atomicAdd(o,         v * w0);
        if (mask & 2u) atomicAdd(o + 1,     v * w1);
        if (mask & 4u) atomicAdd(o + W,     v * w2);
        if (mask & 8u) atomicAdd(o + W + 1, v * w3);
    }
}

// ---- wave-aggregated append: one atomic per (wave, distinct bin) ----
__device__ __forceinline__ bool agg_append(
    bool want, int bin, unsigned nword, unsigned w0, unsigned w1, int wide,
    unsigned* __restrict__ cnt, unsigned* __restrict__ entries, int lane)
{
    bool ovf = false;
    unsigned long long act = __ballot(want);
    while (act) {
        int leader = (int)__builtin_ctzll(act);
        int lbin = __shfl(bin, leader);
        bool mine = want && (bin == lbin);
        unsigned long long grp = __ballot(mine);
        unsigned base = 0;
        if (lane == leader)
            base = atomicAdd(&cnt[(unsigned)lbin * CSTR], (unsigned)__popcll(grp));
        base = (unsigned)__shfl((int)base, leader);
        if (mine) {
            unsigned slot = base + (unsigned)__popcll(grp & ((1ull << lane) - 1ull));
            if (slot < CAP) {
                if (wide)
                    reinterpret_cast<uint2*>(entries)[(size_t)lbin * CAP + slot] =
                        make_uint2(w0, w1);
                else
                    entries[(size_t)lbin * CAP + slot] = nword;
            } else {
                ovf = true;
            }
        }
        act &= ~grp;
    }
    return ovf;
}

// ---------------- Phase 1: bin source pixels by destination tile ----------------
__global__ __launch_bounds__(256) void bin_kernel(
    const float* __restrict__ flow, const float* __restrict__ im0,
    unsigned* __restrict__ cnt, unsigned* __restrict__ entries, int wide,
    float* __restrict__ out)
{
    int idx  = blockIdx.x * 256 + threadIdx.x;   // grid exact: no tail
    int lane = threadIdx.x & 63;
    float2 f = reinterpret_cast<const float2*>(flow)[idx];
    int sx = idx & (W - 1);
    int sy = (idx >> 9) & (H - 1);
    int b  = idx >> 18;

    float xd = (float)sx + f.x;
    float yd = (float)sy + f.y;
    float xff = floorf(xd), yff = floorf(yd);
    // keep only if ALL four corners in-bounds (matches reference)
    bool valid = (xff >= 0.0f && yff >= 0.0f &&
                  xff <= (float)(W - 2) && yff <= (float)(H - 2));
    int xf = valid ? (int)xff : 0;
    int yf = valid ? (int)yff : 0;
    float ax = xd - xff, ay = yd - yff;

    int s = sy * W + sx;
    int d = yf * W + xf;
    unsigned ax14 = min((unsigned)(ax * 16384.0f), 16383u);
    unsigned ay14 = min((unsigned)(ay * 16384.0f), 16383u);
    unsigned w0 = (unsigned)s | (ax14 << 18);   // wide word0
    unsigned w1 = (unsigned)d | (ay14 << 18);   // wide word1

    int txf = xf >> 5, txc = (xf + 1) >> 5;
    int tyf = yf >> 5, tyc = (yf + 1) >> 5;
    bool spx = (txc != txf), spy = (tyc != tyf);
    int binb = b * (TYN * TX);

    unsigned m0 = 1u | (spx ? 0u : 2u) | (spy ? 0u : 4u) | ((!spx && !spy) ? 8u : 0u);
    unsigned m1 = 2u | (spy ? 0u : 8u);
    unsigned m2 = 4u | (spx ? 0u : 8u);
    unsigned m3 = 8u;
    unsigned s4 = (unsigned)s << 4;

    unsigned ovf = 0;
    if (agg_append(valid,               binb + tyf * TX + txf, s4 | m0, w0, w1, wide, cnt, entries, lane)) ovf |= m0;
    if (agg_append(valid && spx,        binb + tyf * TX + txc, s4 | m1, w0, w1, wide, cnt, entries, lane)) ovf |= m1;
    if (agg_append(valid && spy,        binb + tyc * TX + txf, s4 | m2, w0, w1, wide, cnt, entries, lane)) ovf |= m2;
    if (agg_append(valid && spx && spy, binb + tyc * TX + txc, s4 | m3, w0, w1, wide, cnt, entries, lane)) ovf |= m3;

    if (ovf) {  // statistically never
        float u0 = (1.f - ax) * (1.f - ay), u1 = ax * (1.f - ay);
        float u2 = (1.f - ax) * ay,         u3 = ax * ay;
        direct_splat(im0, out, b, s, xf, yf, u0, u1, u2, u3, ovf);
    }
}

// ---------------- Phase 2: per-tile accumulation, CPB channels in LDS ----------------
template <bool WIDE>
__global__ __launch_bounds__(256) void accum_kernel(
    const float* __restrict__ flow, const float* __restrict__ im0,
    const unsigned* __restrict__ cnt, const unsigned* __restrict__ entries,
    float* __restrict__ out)
{
    __shared__ float acc[CPB * TS * TS];   // 32 KB
    const int bin = blockIdx.x;
    const int c0  = blockIdx.y * CPB;
    const int tid = threadIdx.x;
    const int b  = bin >> 8;
    const int ty = (bin >> 4) & 15;
    const int tx = bin & 15;
    const int y0 = ty * TS, x0 = tx * TS;

    for (int i = tid; i < CPB * TS * TS; i += 256) acc[i] = 0.0f;
    __syncthreads();

    const int n = min((int)cnt[bin * CSTR], CAP);
    const float* im0b = im0 + (size_t)b * C * HW + (size_t)c0 * HW;

    for (int i = tid; i < n; i += 256) {
        int s, l0;
        float wnw, wne, wsw, wse;
        bool p0, p1, p2, p3;
        if (WIDE) {
            uint2 e = reinterpret_cast<const uint2*>(entries)[(size_t)bin * CAP + i];
            s      = (int)(e.x & 0x3FFFFu);
            int d  = (int)(e.y & 0x3FFFFu);
            float ax = (float)(e.x >> 18) * (1.0f / 16384.0f);
            float ay = (float)(e.y >> 18) * (1.0f / 16384.0f);
            int xf = d & (W - 1), yf = d >> 9;
            int lx = xf - x0, ly = yf - y0;
            wnw = (1.f - ax) * (1.f - ay); wne = ax * (1.f - ay);
            wsw = (1.f - ax) * ay;         wse = ax * ay;
            p0 = (unsigned)lx < (unsigned)TS && (unsigned)ly < (unsigned)TS;
            p1 = (unsigned)(lx + 1) < (unsigned)TS && (unsigned)ly < (unsigned)TS;
            p2 = (unsigned)lx < (unsigned)TS && (unsigned)(ly + 1) < (unsigned)TS;
            p3 = (unsigned)(lx + 1) < (unsigned)TS && (unsigned)(ly + 1) < (unsigned)TS;
            l0 = ly * TS + lx;
        } else {
            unsigned e = entries[(size_t)bin * CAP + i];
            unsigned mask = e & 15u;
            s = (int)(e >> 4);
            int sx = s & (W - 1), sy = s >> 9;
            float2 f = reinterpret_cast<const float2*>(flow + (size_t)b * HW * 2)[s];
            float xd = (float)sx + f.x, yd = (float)sy + f.y;
            float xff = floorf(xd), yff = floorf(yd);
            int xf = (int)xff, yf = (int)yff;
            float ax = xd - xff, ay = yd - yff;
            wnw = (1.f - ax) * (1.f - ay); wne = ax * (1.f - ay);
            wsw = (1.f - ax) * ay;         wse = ax * ay;
            p0 = mask & 1u; p1 = mask & 2u; p2 = mask & 4u; p3 = mask & 8u;
            l0 = (yf - y0) * TS + (xf - x0);
        }

        float v[CPB];
        #pragma unroll
        for (int c = 0; c < CPB; ++c) v[c] = im0b[(size_t)c * HW + s];

        #pragma unroll
        for (int c = 0; c < CPB; ++c) {
            float* a = acc + c * (TS * TS);
            if (p0) atomicAdd(&a[l0],          v[c] * wnw);
            if (p1) atomicAdd(&a[l0 + 1],      v[c] * wne);
            if (p2) atomicAdd(&a[l0 + TS],     v[c] * wsw);
            if (p3) atomicAdd(&a[l0 + TS + 1], v[c] * wse);
        }
    }
    __syncthreads();

    // flush: exclusive tile ownership -> plain float4 RMW (preserves overflow splats)
    size_t outb = (size_t)b * C * HW + (size_t)c0 * HW;
    constexpr int FL = (CPB * TS * TS) / 4;   // 2048 float4
    for (int i = tid; i < FL; i += 256) {
        int c   = i >> 8;                      // 256 float4 per channel
        int rem = i & 255;
        int y   = rem >> 3;                    // 8 float4 per row
        int x4  = (rem & 7) * 4;
        float4 a = *reinterpret_cast<const float4*>(&acc[c * TS * TS + y * TS + x4]);
        float* op = out + outb + (size_t)c * HW + (size_t)(y0 + y) * W + (x0 + x4);
        float4 cur = *reinterpret_cast<float4*>(op);
        cur.x += a.x; cur.y += a.y; cur.z += a.z; cur.w += a.w;
        *reinterpret_cast<float4*>(op) = cur;
    }
}

// ---------------- Safety fallback: direct-atomic kernel ----------------
__global__ __launch_bounds__(256) void warp_naive_kernel(
    const float* __restrict__ im0, const float* __restrict__ flow,
    float* __restrict__ out)
{
    int idx = blockIdx.x * 256 + threadIdx.x;
    if (idx >= B * HW) return;
    int w = idx & (W - 1);
    int h = (idx >> 9) & (H - 1);
    int b = idx >> 18;
    float2 f = reinterpret_cast<const float2*>(flow)[idx];
    float xd = (float)w + f.x, yd = (float)h + f.y;
    float xff = floorf(xd), yff = floorf(yd);
    if (!(xff >= 0.0f && yff >= 0.0f &&
          xff <= (float)(W - 2) && yff <= (float)(H - 2))) return;
    int xf = (int)xff, yf = (int)yff;
    float ax = xd - xff, ay = yd - yff;
    float w0 = (1.f - ax) * (1.f - ay), w1 = ax * (1.f - ay);
    float w2 = (1.f - ax) * ay,         w3 = ax * ay;
    direct_splat(im0, out, b, h * W + w, xf, yf, w0, w1, w2, w3, 15u);
}

extern "C" void kernel_launch(void* const* d_in, const int* in_sizes, int n_in,
                              void* d_out, int out_size, void* d_ws, size_t ws_size,
                              hipStream_t stream) {
    const float* im0  = (const float*)d_in[0];
    const float* flow = (const float*)d_in[1];
    float* out = (float*)d_out;

    hipMemsetAsync(out, 0, (size_t)out_size * sizeof(float), stream);

    constexpr size_t need_cnt = (size_t)NBINS * CSTR * 4;
    constexpr size_t need8 = need_cnt + (size_t)NBINS * CAP * 8;
    constexpr size_t need4 = need_cnt + (size_t)NBINS * CAP * 4;
    constexpr int total = B * HW;

    if (ws_size < need4) {
        warp_naive_kernel<<<(total + 255) / 256, 256, 0, stream>>>(im0, flow, out);
        return;
    }
    int wide = (ws_size >= need8) ? 1 : 0;

    unsigned* cnt = (unsigned*)d_ws;
    unsigned* entries = cnt + (size_t)NBINS * CSTR;
    hipMemsetAsync(cnt, 0, need_cnt, stream);

    bin_kernel<<<total / 256, 256, 0, stream>>>(flow, im0, cnt, entries, wide, out);

    dim3 agrid(NBINS, C / CPB);
    if (wide)
        accum_kernel<true><<<agrid, 256, 0, stream>>>(flow, im0, cnt, entries, out);
    else
        accum_kernel<false><<<agrid, 256, 0, stream>>>(flow, im0, cnt, entries, out);
}

// Round 5
// 386.821 us; speedup vs baseline: 2.6263x; 1.0067x over previous
//
#include <hip/hip_runtime.h>

constexpr int B = 4, C = 16, H = 512, W = 512;
constexpr int HW = H * W;
constexpr int TS = 32, TX = 16, TYN = 16;
constexpr int NBINS = B * TYN * TX;   // 1024
constexpr int CAP   = 1600;           // slots per bin (expected max ~1250)
constexpr int CSTR  = 16;             // counter stride in u32 -> 64B per counter
constexpr int CPB   = 8;              // channels per accum block (32 KB LDS)

// Native fp32 atomic add (ds_add_f32 / global_atomic_add_f32). Plain
// atomicAdd(float*) lowers to a CAS loop on AMD by default — the round-4
// profile (353us at 1.8% VALU, 0 bank conflicts) is that CAS serialization.
__device__ __forceinline__ void fadd(float* p, float v) { unsafeAtomicAdd(p, v); }

// ---- direct global-atomic splat (overflow / fallback paths) ----
__device__ __forceinline__ void direct_splat(
    const float* __restrict__ im0, float* __restrict__ out,
    int b, int s, int xf, int yf,
    float w0, float w1, float w2, float w3, unsigned mask)
{
    size_t base = (size_t)b * C * HW;
    int d00 = yf * W + xf;
    for (int c = 0; c < C; ++c) {
        float v = im0[base + (size_t)c * HW + s];
        float* o = out + base + (size_t)c * HW + d00;
        if (mask & 1u) fadd(o,         v * w0);
        if (mask & 2u) fadd(o + 1,     v * w1);
        if (mask & 4u) fadd(o + W,     v * w2);
        if (mask & 8u) fadd(o + W + 1, v * w3);
    }
}

// ---- wave-aggregated append: one atomic per (wave, distinct bin) ----
__device__ __forceinline__ bool agg_append(
    bool want, int bin, unsigned nword, unsigned w0, unsigned w1, int wide,
    unsigned* __restrict__ cnt, unsigned* __restrict__ entries, int lane)
{
    bool ovf = false;
    unsigned long long act = __ballot(want);
    while (act) {
        int leader = (int)__builtin_ctzll(act);
        int lbin = __shfl(bin, leader);
        bool mine = want && (bin == lbin);
        unsigned long long grp = __ballot(mine);
        unsigned base = 0;
        if (lane == leader)
            base = atomicAdd(&cnt[(unsigned)lbin * CSTR], (unsigned)__popcll(grp));
        base = (unsigned)__shfl((int)base, leader);
        if (mine) {
            unsigned slot = base + (unsigned)__popcll(grp & ((1ull << lane) - 1ull));
            if (slot < CAP) {
                if (wide)
                    reinterpret_cast<uint2*>(entries)[(size_t)lbin * CAP + slot] =
                        make_uint2(w0, w1);
                else
                    entries[(size_t)lbin * CAP + slot] = nword;
            } else {
                ovf = true;
            }
        }
        act &= ~grp;
    }
    return ovf;
}

// ---------------- Phase 1: bin source pixels by destination tile ----------------
__global__ __launch_bounds__(256) void bin_kernel(
    const float* __restrict__ flow, const float* __restrict__ im0,
    unsigned* __restrict__ cnt, unsigned* __restrict__ entries, int wide,
    float* __restrict__ out)
{
    int idx  = blockIdx.x * 256 + threadIdx.x;   // grid exact: no tail
    int lane = threadIdx.x & 63;
    float2 f = reinterpret_cast<const float2*>(flow)[idx];
    int sx = idx & (W - 1);
    int sy = (idx >> 9) & (H - 1);
    int b  = idx >> 18;

    float xd = (float)sx + f.x;
    float yd = (float)sy + f.y;
    float xff = floorf(xd), yff = floorf(yd);
    // keep only if ALL four corners in-bounds (matches reference)
    bool valid = (xff >= 0.0f && yff >= 0.0f &&
                  xff <= (float)(W - 2) && yff <= (float)(H - 2));
    int xf = valid ? (int)xff : 0;
    int yf = valid ? (int)yff : 0;
    float ax = xd - xff, ay = yd - yff;

    int s = sy * W + sx;
    int d = yf * W + xf;
    unsigned ax14 = min((unsigned)(ax * 16384.0f), 16383u);
    unsigned ay14 = min((unsigned)(ay * 16384.0f), 16383u);
    unsigned w0 = (unsigned)s | (ax14 << 18);   // wide word0
    unsigned w1 = (unsigned)d | (ay14 << 18);   // wide word1

    int txf = xf >> 5, txc = (xf + 1) >> 5;
    int tyf = yf >> 5, tyc = (yf + 1) >> 5;
    bool spx = (txc != txf), spy = (tyc != tyf);
    int binb = b * (TYN * TX);

    unsigned m0 = 1u | (spx ? 0u : 2u) | (spy ? 0u : 4u) | ((!spx && !spy) ? 8u : 0u);
    unsigned m1 = 2u | (spy ? 0u : 8u);
    unsigned m2 = 4u | (spx ? 0u : 8u);
    unsigned m3 = 8u;
    unsigned s4 = (unsigned)s << 4;

    unsigned ovf = 0;
    if (agg_append(valid,               binb + tyf * TX + txf, s4 | m0, w0, w1, wide, cnt, entries, lane)) ovf |= m0;
    if (agg_append(valid && spx,        binb + tyf * TX + txc, s4 | m1, w0, w1, wide, cnt, entries, lane)) ovf |= m1;
    if (agg_append(valid && spy,        binb + tyc * TX + txf, s4 | m2, w0, w1, wide, cnt, entries, lane)) ovf |= m2;
    if (agg_append(valid && spx && spy, binb + tyc * TX + txc, s4 | m3, w0, w1, wide, cnt, entries, lane)) ovf |= m3;

    if (ovf) {  // statistically never
        float u0 = (1.f - ax) * (1.f - ay), u1 = ax * (1.f - ay);
        float u2 = (1.f - ax) * ay,         u3 = ax * ay;
        direct_splat(im0, out, b, s, xf, yf, u0, u1, u2, u3, ovf);
    }
}

// ---------------- Phase 2: per-tile accumulation, CPB channels in LDS ----------------
template <bool WIDE>
__global__ __launch_bounds__(256) void accum_kernel(
    const float* __restrict__ flow, const float* __restrict__ im0,
    const unsigned* __restrict__ cnt, const unsigned* __restrict__ entries,
    float* __restrict__ out)
{
    __shared__ float acc[CPB * TS * TS];   // 32 KB
    const int bin = blockIdx.x;
    const int c0  = blockIdx.y * CPB;
    const int tid = threadIdx.x;
    const int b  = bin >> 8;
    const int ty = (bin >> 4) & 15;
    const int tx = bin & 15;
    const int y0 = ty * TS, x0 = tx * TS;

    for (int i = tid; i < CPB * TS * TS; i += 256) acc[i] = 0.0f;
    __syncthreads();

    const int n = min((int)cnt[bin * CSTR], CAP);
    const float* im0b = im0 + (size_t)b * C * HW + (size_t)c0 * HW;

    for (int i = tid; i < n; i += 256) {
        int s, l0;
        float wnw, wne, wsw, wse;
        bool p0, p1, p2, p3;
        if (WIDE) {
            uint2 e = reinterpret_cast<const uint2*>(entries)[(size_t)bin * CAP + i];
            s      = (int)(e.x & 0x3FFFFu);
            int d  = (int)(e.y & 0x3FFFFu);
            float ax = (float)(e.x >> 18) * (1.0f / 16384.0f);
            float ay = (float)(e.y >> 18) * (1.0f / 16384.0f);
            int xf = d & (W - 1), yf = d >> 9;
            int lx = xf - x0, ly = yf - y0;
            wnw = (1.f - ax) * (1.f - ay); wne = ax * (1.f - ay);
            wsw = (1.f - ax) * ay;         wse = ax * ay;
            p0 = (unsigned)lx < (unsigned)TS && (unsigned)ly < (unsigned)TS;
            p1 = (unsigned)(lx + 1) < (unsigned)TS && (unsigned)ly < (unsigned)TS;
            p2 = (unsigned)lx < (unsigned)TS && (unsigned)(ly + 1) < (unsigned)TS;
            p3 = (unsigned)(lx + 1) < (unsigned)TS && (unsigned)(ly + 1) < (unsigned)TS;
            l0 = ly * TS + lx;
        } else {
            unsigned e = entries[(size_t)bin * CAP + i];
            unsigned mask = e & 15u;
            s = (int)(e >> 4);
            int sx = s & (W - 1), sy = s >> 9;
            float2 f = reinterpret_cast<const float2*>(flow + (size_t)b * HW * 2)[s];
            float xd = (float)sx + f.x, yd = (float)sy + f.y;
            float xff = floorf(xd), yff = floorf(yd);
            int xf = (int)xff, yf = (int)yff;
            float ax = xd - xff, ay = yd - yff;
            wnw = (1.f - ax) * (1.f - ay); wne = ax * (1.f - ay);
            wsw = (1.f - ax) * ay;         wse = ax * ay;
            p0 = mask & 1u; p1 = mask & 2u; p2 = mask & 4u; p3 = mask & 8u;
            l0 = (yf - y0) * TS + (xf - x0);
        }

        float v[CPB];
        #pragma unroll
        for (int c = 0; c < CPB; ++c) v[c] = im0b[(size_t)c * HW + s];

        #pragma unroll
        for (int c = 0; c < CPB; ++c) {
            float* a = acc + c * (TS * TS);
            if (p0) fadd(&a[l0],          v[c] * wnw);
            if (p1) fadd(&a[l0 + 1],      v[c] * wne);
            if (p2) fadd(&a[l0 + TS],     v[c] * wsw);
            if (p3) fadd(&a[l0 + TS + 1], v[c] * wse);
        }
    }
    __syncthreads();

    // flush: exclusive tile ownership -> plain float4 RMW (preserves overflow splats)
    size_t outb = (size_t)b * C * HW + (size_t)c0 * HW;
    constexpr int FL = (CPB * TS * TS) / 4;   // 2048 float4
    for (int i = tid; i < FL; i += 256) {
        int c   = i >> 8;                      // 256 float4 per channel
        int rem = i & 255;
        int y   = rem >> 3;                    // 8 float4 per row
        int x4  = (rem & 7) * 4;
        float4 a = *reinterpret_cast<const float4*>(&acc[c * TS * TS + y * TS + x4]);
        float* op = out + outb + (size_t)c * HW + (size_t)(y0 + y) * W + (x0 + x4);
        float4 cur = *reinterpret_cast<float4*>(op);
        cur.x += a.x; cur.y += a.y; cur.z += a.z; cur.w += a.w;
        *reinterpret_cast<float4*>(op) = cur;
    }
}

// ---------------- Safety fallback: direct-atomic kernel ----------------
__global__ __launch_bounds__(256) void warp_naive_kernel(
    const float* __restrict__ im0, const float* __restrict__ flow,
    float* __restrict__ out)
{
    int idx = blockIdx.x * 256 + threadIdx.x;
    if (idx >= B * HW) return;
    int w = idx & (W - 1);
    int h = (idx >> 9) & (H - 1);
    int b = idx >> 18;
    float2 f = reinterpret_cast<const float2*>(flow)[idx];
    float xd = (float)w + f.x, yd = (float)h + f.y;
    float xff = floorf(xd), yff = floorf(yd);
    if (!(xff >= 0.0f && yff >= 0.0f &&
          xff <= (float)(W - 2) && yff <= (float)(H - 2))) return;
    int xf = (int)xff, yf = (int)yff;
    float ax = xd - xff, ay = yd - yff;
    float w0 = (1.f - ax) * (1.f - ay), w1 = ax * (1.f - ay);
    float w2 = (1.f - ax) * ay,         w3 = ax * ay;
    direct_splat(im0, out, b, h * W + w, xf, yf, w0, w1, w2, w3, 15u);
}

extern "C" void kernel_launch(void* const* d_in, const int* in_sizes, int n_in,
                              void* d_out, int out_size, void* d_ws, size_t ws_size,
                              hipStream_t stream) {
    const float* im0  = (const float*)d_in[0];
    const float* flow = (const float*)d_in[1];
    float* out = (float*)d_out;

    hipMemsetAsync(out, 0, (size_t)out_size * sizeof(float), stream);

    constexpr size_t need_cnt = (size_t)NBINS * CSTR * 4;
    constexpr size_t need8 = need_cnt + (size_t)NBINS * CAP * 8;
    constexpr size_t need4 = need_cnt + (size_t)NBINS * CAP * 4;
    constexpr int total = B * HW;

    if (ws_size < need4) {
        warp_naive_kernel<<<(total + 255) / 256, 256, 0, stream>>>(im0, flow, out);
        return;
    }
    int wide = (ws_size >= need8) ? 1 : 0;

    unsigned* cnt = (unsigned*)d_ws;
    unsigned* entries = cnt + (size_t)NBINS * CSTR;
    hipMemsetAsync(cnt, 0, need_cnt, stream);

    bin_kernel<<<total / 256, 256, 0, stream>>>(flow, im0, cnt, entries, wide, out);

    dim3 agrid(NBINS, C / CPB);
    if (wide)
        accum_kernel<true><<<agrid, 256, 0, stream>>>(flow, im0, cnt, entries, out);
    else
        accum_kernel<false><<<agrid, 256, 0, stream>>>(flow, im0, cnt, entries, out);
}